// Round 2
// baseline (1025.312 us; speedup 1.0000x reference)
//
#include <hip/hip_runtime.h>

#define KP    3136   // 3072 quant + 32 lora + 32 zero-pad
#define CDIM  3072
#define MROWS 8192
#define NOUT  9216
#define NQK   6144

typedef __bf16 bf16x8 __attribute__((ext_vector_type(8)));
typedef float f32x4 __attribute__((ext_vector_type(4)));

__device__ __forceinline__ unsigned short f2bf(float f) {
  union { float f; unsigned int u; } v; v.f = f;
  unsigned int u = v.u;
  return (unsigned short)((u + 0x7fffu + ((u >> 16) & 1u)) >> 16);  // RNE
}
__device__ __forceinline__ void gld16(const void* g, void* l) {
  __builtin_amdgcn_global_load_lds(
      (const __attribute__((address_space(1))) void*)g,
      (__attribute__((address_space(3))) void*)l, 16, 0, 0);
}

// ---------------- K1: weight fake-quant + proj_up pack -> Bp[9216][3136] bf16
__global__ void k_wquant(const float* __restrict__ w, const float* __restrict__ pu,
                         unsigned short* __restrict__ Bp) {
  const int wid = blockIdx.x * 4 + (threadIdx.x >> 6);
  const int l = threadIdx.x & 63;
  const int row = wid / 49, g = wid - row * 49;
  if (g == 48) {  // tail: [3072,3104)=proj_up row, [3104,3136)=0
    Bp[(size_t)row * KP + CDIM + l] = (l < 32) ? f2bf(pu[row * 32 + l]) : (unsigned short)0;
    return;
  }
  const int c = g * 64 + l;
  const float v = w[(size_t)row * CDIM + c];
  float am = fabsf(v);
  #pragma unroll
  for (int off = 32; off; off >>= 1) am = fmaxf(am, __shfl_xor(am, off));
  const float s = fmaxf(am / 7.0f, 1e-8f);                 // IEEE div, matches np
  const float q = fminf(fmaxf(rintf(v / s), -8.0f), 7.0f) * s;  // rintf = half-even
  Bp[(size_t)row * KP + c] = f2bf(q);
}

// ---------------- K2a: activation smooth+fake-quant -> Ap[8192][3136] bf16 (cols 0..3071, 3104..3135)
__global__ void k_aquant(const float* __restrict__ x, const float* __restrict__ smooth,
                         unsigned short* __restrict__ Ap) {
  const int wid = blockIdx.x * 4 + (threadIdx.x >> 6);
  const int l = threadIdx.x & 63;
  const int row = wid / 49, g = wid - row * 49;
  if (g == 48) {
    if (l >= 32) Ap[(size_t)row * KP + CDIM + l] = 0;  // zero pad; lora cols written by k_lora
    return;
  }
  const int c = g * 64 + l;
  const float xs = x[(size_t)row * CDIM + c] / smooth[c];  // IEEE div
  float am = fabsf(xs);
  #pragma unroll
  for (int off = 32; off; off >>= 1) am = fmaxf(am, __shfl_xor(am, off));
  const float s = fmaxf(am / 7.0f, 1e-8f);
  const float q = fminf(fmaxf(rintf(xs / s), -8.0f), 7.0f) * s;
  Ap[(size_t)row * KP + c] = f2bf(q);
}

// ---------------- K2b: lora_act = (x/smooth) @ proj_down -> Ap cols [3072,3104) bf16
// block = 256 threads = 32 rows x 8 r-groups (4 outputs each)
__global__ void k_lora(const float* __restrict__ x, const float* __restrict__ smooth,
                       const float* __restrict__ pd, unsigned short* __restrict__ Ap) {
  const int row = blockIdx.x * 32 + (threadIdx.x >> 3);
  const int rg = (threadIdx.x & 7) * 4;
  const float* xr = x + (size_t)row * CDIM;
  float a0 = 0.f, a1 = 0.f, a2 = 0.f, a3 = 0.f;
  for (int c = 0; c < CDIM; c += 4) {
    const float4 xv = *(const float4*)&xr[c];
    const float4 sm = *(const float4*)&smooth[c];
    const float x0 = xv.x * __builtin_amdgcn_rcpf(sm.x);
    const float x1 = xv.y * __builtin_amdgcn_rcpf(sm.y);
    const float x2 = xv.z * __builtin_amdgcn_rcpf(sm.z);
    const float x3 = xv.w * __builtin_amdgcn_rcpf(sm.w);
    const float4 p0 = *(const float4*)&pd[(size_t)(c + 0) * 32 + rg];
    const float4 p1 = *(const float4*)&pd[(size_t)(c + 1) * 32 + rg];
    const float4 p2 = *(const float4*)&pd[(size_t)(c + 2) * 32 + rg];
    const float4 p3 = *(const float4*)&pd[(size_t)(c + 3) * 32 + rg];
    a0 += x0 * p0.x + x1 * p1.x + x2 * p2.x + x3 * p3.x;
    a1 += x0 * p0.y + x1 * p1.y + x2 * p2.y + x3 * p3.y;
    a2 += x0 * p0.z + x1 * p1.z + x2 * p2.z + x3 * p3.z;
    a3 += x0 * p0.w + x1 * p1.w + x2 * p2.w + x3 * p3.w;
  }
  const size_t base = (size_t)row * KP + CDIM + rg;
  Ap[base + 0] = f2bf(a0);
  Ap[base + 1] = f2bf(a1);
  Ap[base + 2] = f2bf(a2);
  Ap[base + 3] = f2bf(a3);
}

// ---------------- K3: C = Ap @ Bp^T + bias -> d_out (f32), 128x128 tile, BK=64
__global__ __launch_bounds__(256, 2) void k_gemm(
    const unsigned short* __restrict__ Ap, const unsigned short* __restrict__ Bp,
    const float* __restrict__ bias, float* __restrict__ outp) {
  __shared__ alignas(16) unsigned short As[128 * 64];
  __shared__ alignas(16) unsigned short Bs[128 * 64];
  const int tid = threadIdx.x;
  const int w = tid >> 6, l = tid & 63;
  const int wr = w >> 1, wc = w & 1;
  const int n0 = blockIdx.x * 128;
  const int m0 = blockIdx.y * 128;

  f32x4 acc[4][4] = {};

  const int srow = tid >> 3;           // 0..31
  const int scol = (tid & 7) * 8;      // 0..56 (bf16 elems)
  const unsigned short* Ab = Ap + (size_t)(m0 + srow) * KP + scol;
  const unsigned short* Bb = Bp + (size_t)(n0 + srow) * KP + scol;

  for (int kt = 0; kt < KP / 64; ++kt) {
    const int k0 = kt * 64;
    #pragma unroll
    for (int i = 0; i < 4; ++i) {
      gld16(Ab + (size_t)(i * 32) * KP + k0, &As[(i * 256 + tid) * 8]);
      gld16(Bb + (size_t)(i * 32) * KP + k0, &Bs[(i * 256 + tid) * 8]);
    }
    __syncthreads();
    #pragma unroll
    for (int kk = 0; kk < 2; ++kk) {
      bf16x8 af[4], bfr[4];
      #pragma unroll
      for (int mi = 0; mi < 4; ++mi)
        af[mi] = *(const bf16x8*)&As[(wr * 64 + mi * 16 + (l & 15)) * 64 + kk * 32 + (l >> 4) * 8];
      #pragma unroll
      for (int ni = 0; ni < 4; ++ni)
        bfr[ni] = *(const bf16x8*)&Bs[(wc * 64 + ni * 16 + (l & 15)) * 64 + kk * 32 + (l >> 4) * 8];
      #pragma unroll
      for (int mi = 0; mi < 4; ++mi)
        #pragma unroll
        for (int ni = 0; ni < 4; ++ni)
          acc[mi][ni] = __builtin_amdgcn_mfma_f32_16x16x32_bf16(af[mi], bfr[ni], acc[mi][ni], 0, 0, 0);
    }
    __syncthreads();
  }

  #pragma unroll
  for (int ni = 0; ni < 4; ++ni) {
    const int gn = n0 + wc * 64 + ni * 16 + (l & 15);
    const float bv = bias[gn];
    #pragma unroll
    for (int mi = 0; mi < 4; ++mi) {
      const int gm = m0 + wr * 64 + mi * 16 + (l >> 4) * 4;
      #pragma unroll
      for (int j = 0; j < 4; ++j)
        outp[(size_t)(gm + j) * NOUT + gn] = acc[mi][ni][j] + bv;
    }
  }
}

// ---------------- K4: in-place RMSNorm + RoPE on q,k columns of d_out (f32)
// block per row m; wave w handles head-slots w, w+4, ... (48 slots: 24 q + 24 k)
__global__ void k_epi(float* __restrict__ outp,
                      const float* __restrict__ nqw, const float* __restrict__ nkw,
                      const float* __restrict__ fcos, const float* __restrict__ fsin) {
  const int m = blockIdx.x;
  const int sidx = m & 4095;           // m = b*4096 + s
  const int w = threadIdx.x >> 6, l = threadIdx.x & 63;
  const float cv = fcos[(size_t)sidx * 64 + l];
  const float sv = fsin[(size_t)sidx * 64 + l];
  const float2 wq = *(const float2*)&nqw[2 * l];
  const float2 wk = *(const float2*)&nkw[2 * l];
  for (int hh = w; hh < 48; hh += 4) {
    float* p = outp + (size_t)m * NOUT + hh * 128 + 2 * l;
    float2 ab = *(const float2*)p;
    float a = ab.x, b = ab.y;
    float ss = a * a + b * b;
    #pragma unroll
    for (int off = 32; off; off >>= 1) ss += __shfl_xor(ss, off);
    const float rinv = 1.0f / sqrtf(ss * (1.0f / 128.0f) + 1e-6f);
    const float2 nw = (hh < 24) ? wq : wk;
    a = a * rinv * nw.x;
    b = b * rinv * nw.y;
    float2 o;
    o.x = a * cv - b * sv;
    o.y = a * sv + b * cv;
    *(float2*)p = o;
  }
}

extern "C" void kernel_launch(void* const* d_in, const int* in_sizes, int n_in,
                              void* d_out, int out_size, void* d_ws, size_t ws_size,
                              hipStream_t stream) {
  const float* x      = (const float*)d_in[0];
  const float* smooth = (const float*)d_in[1];
  const float* weight = (const float*)d_in[2];
  const float* pd     = (const float*)d_in[3];
  const float* pu     = (const float*)d_in[4];
  const float* bias   = (const float*)d_in[5];
  const float* nqw    = (const float*)d_in[6];
  const float* nkw    = (const float*)d_in[7];
  const float* fcos   = (const float*)d_in[8];
  const float* fsin   = (const float*)d_in[9];
  float* out = (float*)d_out;

  unsigned short* Ap = (unsigned short*)d_ws;                              // 8192*3136*2 = 51,380,224 B
  unsigned short* Bp = (unsigned short*)((char*)d_ws + 51380224);          // 9216*3136*2 = 57,802,752 B

  k_wquant<<<dim3(9216 * 49 / 4), dim3(256), 0, stream>>>(weight, pu, Bp);
  k_aquant<<<dim3(8192 * 49 / 4), dim3(256), 0, stream>>>(x, smooth, Ap);
  k_lora<<<dim3(8192 / 32), dim3(256), 0, stream>>>(x, smooth, pd, Ap);
  k_gemm<<<dim3(NOUT / 128, MROWS / 128), dim3(256), 0, stream>>>(Ap, Bp, bias, out);
  k_epi<<<dim3(MROWS), dim3(256), 0, stream>>>(out, nqw, nkw, fcos, fsin);
}

// Round 3
// 806.613 us; speedup vs baseline: 1.2711x; 1.2711x over previous
//
#include <hip/hip_runtime.h>

#define KP    3136   // 3072 quant + 32 lora + 32 zero-pad
#define CDIM  3072
#define MROWS 8192
#define NOUT  9216
#define NT    49     // KP / 64 K-tiles

typedef __bf16 bf16x8 __attribute__((ext_vector_type(8)));
typedef float f32x4 __attribute__((ext_vector_type(4)));

__device__ __forceinline__ unsigned short f2bf(float f) {
  union { float f; unsigned int u; } v; v.f = f;
  unsigned int u = v.u;
  return (unsigned short)((u + 0x7fffu + ((u >> 16) & 1u)) >> 16);  // RNE
}
__device__ __forceinline__ float bfu_lo(unsigned int u) {
  union { unsigned int v; float f; } x; x.v = u << 16; return x.f;
}
__device__ __forceinline__ float bfu_hi(unsigned int u) {
  union { unsigned int v; float f; } x; x.v = u & 0xffff0000u; return x.f;
}
__device__ __forceinline__ void gld16(const void* g, void* l) {
  __builtin_amdgcn_global_load_lds(
      (const __attribute__((address_space(1))) void*)g,
      (__attribute__((address_space(3))) void*)l, 16, 0, 0);
}

#define BARRIER() asm volatile("s_barrier" ::: "memory")
#define LGKM0()   asm volatile("s_waitcnt lgkmcnt(0)" ::: "memory")
#define VMC(n)    asm volatile("s_waitcnt vmcnt(" #n ")" ::: "memory")

// ---------------- K1: weight fake-quant + proj_up pack -> Bp[9216][3136] bf16
__global__ void k_wquant(const float* __restrict__ w, const float* __restrict__ pu,
                         unsigned short* __restrict__ Bp) {
  const int wid = blockIdx.x * 4 + (threadIdx.x >> 6);
  const int l = threadIdx.x & 63;
  const int row = wid / 49, g = wid - row * 49;
  if (g == 48) {  // tail: [3072,3104)=proj_up row, [3104,3136)=0
    Bp[(size_t)row * KP + CDIM + l] = (l < 32) ? f2bf(pu[row * 32 + l]) : (unsigned short)0;
    return;
  }
  const int c = g * 64 + l;
  const float v = w[(size_t)row * CDIM + c];
  float am = fabsf(v);
  #pragma unroll
  for (int off = 32; off; off >>= 1) am = fmaxf(am, __shfl_xor(am, off));
  const float s = fmaxf(am / 7.0f, 1e-8f);                      // IEEE div
  const float q = fminf(fmaxf(rintf(v / s), -8.0f), 7.0f) * s;  // rintf = half-even
  Bp[(size_t)row * KP + c] = f2bf(q);
}

// ---------------- K2: activation smooth + fake-quant + lora -> Ap[8192][3136]
// block = 4 rows; wave w owns row w. Quant phase stores xs (bf16) to LDS; lora
// phase computes lora_act = xs @ pd with pd read once per block (L2-hot).
__global__ __launch_bounds__(256) void k_aprep(const float* __restrict__ x,
                                               const float* __restrict__ smooth,
                                               const float* __restrict__ pd,
                                               unsigned short* __restrict__ Ap) {
  __shared__ unsigned short xsb[4][3072];   // 24 KB
  __shared__ float plds[4][32][33];         // 16.5 KB
  const int tid = threadIdx.x;
  const int w = tid >> 6, l = tid & 63;
  const int row = blockIdx.x * 4 + w;
  const float* xr = x + (size_t)row * CDIM;

  for (int g = 0; g < 48; ++g) {
    const int c = g * 64 + l;
    const float xs = xr[c] / smooth[c];     // exact IEEE div
    xsb[w][c] = f2bf(xs);
    float am = fabsf(xs);
    #pragma unroll
    for (int off = 32; off; off >>= 1) am = fmaxf(am, __shfl_xor(am, off));
    const float s = fmaxf(am / 7.0f, 1e-8f);
    const float q = fminf(fmaxf(rintf(xs / s), -8.0f), 7.0f) * s;
    Ap[(size_t)row * KP + c] = f2bf(q);
  }
  if (l < 32) Ap[(size_t)row * KP + 3104 + l] = 0;  // zero pad cols
  __syncthreads();

  // lora: thread (ch=tid>>3 in [0,32), rg=tid&7): c = ch*2 + 64*i (+0,+1)
  const int ch = tid >> 3, rg = tid & 7;
  float acc[4][4] = {};
  for (int i = 0; i < 48; ++i) {
    const int c = ch * 2 + i * 64;
    const float4 p0 = *(const float4*)&pd[(size_t)c * 32 + rg * 4];
    const float4 p1 = *(const float4*)&pd[(size_t)(c + 1) * 32 + rg * 4];
    #pragma unroll
    for (int r4 = 0; r4 < 4; ++r4) {
      const unsigned int u = *(const unsigned int*)&xsb[r4][c];
      const float xa = bfu_lo(u), xb = bfu_hi(u);
      acc[r4][0] += xa * p0.x + xb * p1.x;
      acc[r4][1] += xa * p0.y + xb * p1.y;
      acc[r4][2] += xa * p0.z + xb * p1.z;
      acc[r4][3] += xa * p0.w + xb * p1.w;
    }
  }
  #pragma unroll
  for (int r4 = 0; r4 < 4; ++r4)
    #pragma unroll
    for (int j = 0; j < 4; ++j)
      plds[r4][rg * 4 + j][ch] = acc[r4][j];
  __syncthreads();
  if (tid < 128) {
    const int rr = tid >> 5, r = tid & 31;
    float ssum = 0.f;
    #pragma unroll
    for (int cc = 0; cc < 32; ++cc) ssum += plds[rr][r][cc];
    Ap[(size_t)(blockIdx.x * 4 + rr) * KP + 3072 + r] = f2bf(ssum);
  }
}

// ---------------- K3: 256x256-tile GEMM, BK=64 (kk-half regions), counted vmcnt
// LDS regions (elements): A(kk,par) = (kk*2+par)*8192 ; B at +32768.
// Region layout [256 rows][32 cols] with 16B-slot XOR swizzle: slot ^= row&3.
__device__ __forceinline__ void gemm_window(
    unsigned short* lds, f32x4 (&acc)[8][4],
    const unsigned short* Asrc, const unsigned short* Bsrc,
    int tid, int arow, int brow, int fsl,
    int par, int t, int do01, int do23, int last) {
  const int A0 = par * 8192;
  const int A1 = 16384 + par * 8192;
  const int B0 = 32768 + par * 8192;
  const int B1 = 49152 + par * 8192;
  const int A1n = 16384 + (par ^ 1) * 8192;
  const int B1n = 49152 + (par ^ 1) * 8192;
  bf16x8 a[4], b[4];

  // ---- phase 0: kk0, mi 0-3 (+ stage A-kk1 of tile t+1)
  #pragma unroll
  for (int ni = 0; ni < 4; ++ni) b[ni] = *(const bf16x8*)&lds[B0 + (brow + ni * 16) * 32 + fsl];
  #pragma unroll
  for (int mi = 0; mi < 4; ++mi) a[mi] = *(const bf16x8*)&lds[A0 + (arow + mi * 16) * 32 + fsl];
  if (do01) {
    const int kc = (t + 1) * 64 + 32;
    gld16(Asrc + kc, &lds[A1n + tid * 8]);
    gld16(Asrc + (size_t)128 * KP + kc, &lds[A1n + 4096 + tid * 8]);
  }
  BARRIER(); LGKM0();
  __builtin_amdgcn_s_setprio(1);
  #pragma unroll
  for (int mi = 0; mi < 4; ++mi)
    #pragma unroll
    for (int ni = 0; ni < 4; ++ni)
      acc[mi][ni] = __builtin_amdgcn_mfma_f32_16x16x32_bf16(a[mi], b[ni], acc[mi][ni], 0, 0, 0);
  __builtin_amdgcn_s_setprio(0);
  BARRIER();

  // ---- phase 1: kk0, mi 4-7 (+ stage B-kk1 of tile t+1; vmcnt)
  #pragma unroll
  for (int mi = 0; mi < 4; ++mi) a[mi] = *(const bf16x8*)&lds[A0 + (arow + 64 + mi * 16) * 32 + fsl];
  if (do01) {
    const int kc = (t + 1) * 64 + 32;
    gld16(Bsrc + kc, &lds[B1n + tid * 8]);
    gld16(Bsrc + (size_t)128 * KP + kc, &lds[B1n + 4096 + tid * 8]);
  }
  BARRIER(); LGKM0();
  __builtin_amdgcn_s_setprio(1);
  #pragma unroll
  for (int mi = 0; mi < 4; ++mi)
    #pragma unroll
    for (int ni = 0; ni < 4; ++ni)
      acc[4 + mi][ni] = __builtin_amdgcn_mfma_f32_16x16x32_bf16(a[mi], b[ni], acc[4 + mi][ni], 0, 0, 0);
  __builtin_amdgcn_s_setprio(0);
  if (last) { VMC(0); } else { VMC(4); }
  BARRIER();

  // ---- phase 2: kk1, mi 0-3 (+ stage A-kk0 of tile t+2 into this tile's A-kk0)
  #pragma unroll
  for (int ni = 0; ni < 4; ++ni) b[ni] = *(const bf16x8*)&lds[B1 + (brow + ni * 16) * 32 + fsl];
  #pragma unroll
  for (int mi = 0; mi < 4; ++mi) a[mi] = *(const bf16x8*)&lds[A1 + (arow + mi * 16) * 32 + fsl];
  if (do23) {
    const int kc = (t + 2) * 64;
    gld16(Asrc + kc, &lds[A0 + tid * 8]);
    gld16(Asrc + (size_t)128 * KP + kc, &lds[A0 + 4096 + tid * 8]);
  }
  BARRIER(); LGKM0();
  __builtin_amdgcn_s_setprio(1);
  #pragma unroll
  for (int mi = 0; mi < 4; ++mi)
    #pragma unroll
    for (int ni = 0; ni < 4; ++ni)
      acc[mi][ni] = __builtin_amdgcn_mfma_f32_16x16x32_bf16(a[mi], b[ni], acc[mi][ni], 0, 0, 0);
  __builtin_amdgcn_s_setprio(0);
  BARRIER();

  // ---- phase 3: kk1, mi 4-7 (+ stage B-kk0 of tile t+2)
  #pragma unroll
  for (int mi = 0; mi < 4; ++mi) a[mi] = *(const bf16x8*)&lds[A1 + (arow + 64 + mi * 16) * 32 + fsl];
  if (do23) {
    const int kc = (t + 2) * 64;
    gld16(Bsrc + kc, &lds[B0 + tid * 8]);
    gld16(Bsrc + (size_t)128 * KP + kc, &lds[B0 + 4096 + tid * 8]);
  }
  BARRIER(); LGKM0();
  __builtin_amdgcn_s_setprio(1);
  #pragma unroll
  for (int mi = 0; mi < 4; ++mi)
    #pragma unroll
    for (int ni = 0; ni < 4; ++ni)
      acc[4 + mi][ni] = __builtin_amdgcn_mfma_f32_16x16x32_bf16(a[mi], b[ni], acc[4 + mi][ni], 0, 0, 0);
  __builtin_amdgcn_s_setprio(0);
  BARRIER();
}

__global__ __launch_bounds__(512, 2) void k_gemm8(
    const unsigned short* __restrict__ Ap, const unsigned short* __restrict__ Bp,
    const float* __restrict__ bias, float* __restrict__ outp) {
  __shared__ unsigned short lds[65536];  // 128 KiB
  const int tid = threadIdx.x;
  const int w = tid >> 6, l = tid & 63;
  const int wr = w >> 2, wc = w & 3;               // 2M x 4N waves, 128x64 each
  const int s = ((blockIdx.x & 7) * 144) + (blockIdx.x >> 3);  // XCD swizzle (1152%8==0)
  const int bx = s % 36, by = s / 36;
  const int n0 = bx * 256, m0 = by * 256;
  const int arow = wr * 128 + (l & 15);
  const int brow = wc * 64 + (l & 15);
  const int fsl = (((l >> 4) ^ (l & 3)) << 3);     // swizzled 16B-slot (elements)
  const int sr = tid >> 2;                          // staging row 0..127
  const int ss = (((tid & 3) ^ (sr & 3)) << 3);     // pre-swizzled source slot
  const unsigned short* Asrc = Ap + (size_t)(m0 + sr) * KP + ss;
  const unsigned short* Bsrc = Bp + (size_t)(n0 + sr) * KP + ss;
  f32x4 acc[8][4] = {};

  // prologue: stage Ak0(0),Bk0(0),Ak1(0),Bk1(0),Ak0(1),Bk0(1); retire tile 0
  gld16(Asrc, &lds[tid * 8]);                 gld16(Asrc + (size_t)128 * KP, &lds[4096 + tid * 8]);
  gld16(Bsrc, &lds[32768 + tid * 8]);         gld16(Bsrc + (size_t)128 * KP, &lds[36864 + tid * 8]);
  gld16(Asrc + 32, &lds[16384 + tid * 8]);    gld16(Asrc + (size_t)128 * KP + 32, &lds[20480 + tid * 8]);
  gld16(Bsrc + 32, &lds[49152 + tid * 8]);    gld16(Bsrc + (size_t)128 * KP + 32, &lds[53248 + tid * 8]);
  gld16(Asrc + 64, &lds[8192 + tid * 8]);     gld16(Asrc + (size_t)128 * KP + 64, &lds[12288 + tid * 8]);
  gld16(Bsrc + 64, &lds[40960 + tid * 8]);    gld16(Bsrc + (size_t)128 * KP + 64, &lds[45056 + tid * 8]);
  VMC(4); BARRIER();

  #pragma unroll 1
  for (int t = 0; t <= NT - 3; ++t)
    gemm_window(lds, acc, Asrc, Bsrc, tid, arow, brow, fsl, t & 1, t, 1, 1, 0);
  gemm_window(lds, acc, Asrc, Bsrc, tid, arow, brow, fsl, (NT - 2) & 1, NT - 2, 1, 0, 0);
  gemm_window(lds, acc, Asrc, Bsrc, tid, arow, brow, fsl, (NT - 1) & 1, NT - 1, 0, 0, 1);

  #pragma unroll
  for (int ni = 0; ni < 4; ++ni) {
    const int gn = n0 + wc * 64 + ni * 16 + (l & 15);
    const float bv = bias[gn];
    #pragma unroll
    for (int q = 0; q < 8; ++q) {
      const int gm = m0 + wr * 128 + q * 16 + (l >> 4) * 4;
      #pragma unroll
      for (int j = 0; j < 4; ++j)
        outp[(size_t)(gm + j) * NOUT + gn] = acc[q][ni][j] + bv;
    }
  }
}

// ---------------- K4: in-place RMSNorm + RoPE on q,k columns of d_out (f32)
__global__ void k_epi(float* __restrict__ outp,
                      const float* __restrict__ nqw, const float* __restrict__ nkw,
                      const float* __restrict__ fcos, const float* __restrict__ fsin) {
  const int m = blockIdx.x;
  const int sidx = m & 4095;           // m = b*4096 + s
  const int w = threadIdx.x >> 6, l = threadIdx.x & 63;
  const float cv = fcos[(size_t)sidx * 64 + l];
  const float sv = fsin[(size_t)sidx * 64 + l];
  const float2 wq = *(const float2*)&nqw[2 * l];
  const float2 wk = *(const float2*)&nkw[2 * l];
  for (int hh = w; hh < 48; hh += 4) {
    float* p = outp + (size_t)m * NOUT + hh * 128 + 2 * l;
    float2 ab = *(const float2*)p;
    float a = ab.x, b = ab.y;
    float ss = a * a + b * b;
    #pragma unroll
    for (int off = 32; off; off >>= 1) ss += __shfl_xor(ss, off);
    const float rinv = 1.0f / sqrtf(ss * (1.0f / 128.0f) + 1e-6f);
    const float2 nw = (hh < 24) ? wq : wk;
    a = a * rinv * nw.x;
    b = b * rinv * nw.y;
    float2 o;
    o.x = a * cv - b * sv;
    o.y = a * sv + b * cv;
    *(float2*)p = o;
  }
}

extern "C" void kernel_launch(void* const* d_in, const int* in_sizes, int n_in,
                              void* d_out, int out_size, void* d_ws, size_t ws_size,
                              hipStream_t stream) {
  const float* x      = (const float*)d_in[0];
  const float* smooth = (const float*)d_in[1];
  const float* weight = (const float*)d_in[2];
  const float* pd     = (const float*)d_in[3];
  const float* pu     = (const float*)d_in[4];
  const float* bias   = (const float*)d_in[5];
  const float* nqw    = (const float*)d_in[6];
  const float* nkw    = (const float*)d_in[7];
  const float* fcos   = (const float*)d_in[8];
  const float* fsin   = (const float*)d_in[9];
  float* out = (float*)d_out;

  unsigned short* Ap = (unsigned short*)d_ws;                      // 51,380,224 B
  unsigned short* Bp = (unsigned short*)((char*)d_ws + 51380224);  // 57,802,752 B

  k_wquant<<<dim3(9216 * 49 / 4), dim3(256), 0, stream>>>(weight, pu, Bp);
  k_aprep<<<dim3(MROWS / 4), dim3(256), 0, stream>>>(x, smooth, pd, Ap);
  k_gemm8<<<dim3(1152), dim3(512), 0, stream>>>(Ap, Bp, bias, out);
  k_epi<<<dim3(MROWS), dim3(256), 0, stream>>>(out, nqw, nkw, fcos, fsin);
}

// Round 4
// 668.154 us; speedup vs baseline: 1.5345x; 1.2072x over previous
//
#include <hip/hip_runtime.h>

#define KP    3136   // 3072 quant + 32 lora + 32 zero-pad
#define CDIM  3072
#define MROWS 8192
#define NOUT  9216
#define NT    49     // KP / 64 K-tiles

typedef __bf16 bf16x8 __attribute__((ext_vector_type(8)));
typedef float f32x4 __attribute__((ext_vector_type(4)));

__device__ __forceinline__ unsigned short f2bf(float f) {
  union { float f; unsigned int u; } v; v.f = f;
  unsigned int u = v.u;
  return (unsigned short)((u + 0x7fffu + ((u >> 16) & 1u)) >> 16);  // RNE
}
__device__ __forceinline__ float bfu_lo(unsigned int u) {
  union { unsigned int v; float f; } x; x.v = u << 16; return x.f;
}
__device__ __forceinline__ float bfu_hi(unsigned int u) {
  union { unsigned int v; float f; } x; x.v = u & 0xffff0000u; return x.f;
}
__device__ __forceinline__ void gld16(const void* g, void* l) {
  __builtin_amdgcn_global_load_lds(
      (const __attribute__((address_space(1))) void*)g,
      (__attribute__((address_space(3))) void*)l, 16, 0, 0);
}

#define BARRIER() asm volatile("s_barrier" ::: "memory")
#define LGKM0()   asm volatile("s_waitcnt lgkmcnt(0)" ::: "memory")

template<int N> __device__ __forceinline__ void vmw() {
  if constexpr (N == 8)      asm volatile("s_waitcnt vmcnt(8)" ::: "memory");
  else if constexpr (N == 4) asm volatile("s_waitcnt vmcnt(4)" ::: "memory");
  else if constexpr (N == 0) asm volatile("s_waitcnt vmcnt(0)" ::: "memory");
  // N==63: no wait
}

// ---------------- K1: weight fake-quant + proj_up pack -> Bp[9216][3136] bf16
// one block per row; float4/lane, group=64 -> 16-lane reduce
__global__ __launch_bounds__(256) void k_wquant(const float* __restrict__ w,
                                                const float* __restrict__ pu,
                                                unsigned short* __restrict__ Bp) {
  const int row = blockIdx.x;
  const int tid = threadIdx.x;
  #pragma unroll
  for (int it = 0; it < 3; ++it) {
    const int c = it * 1024 + tid * 4;
    const float4 v = *(const float4*)&w[(size_t)row * CDIM + c];
    float am = fmaxf(fmaxf(fabsf(v.x), fabsf(v.y)), fmaxf(fabsf(v.z), fabsf(v.w)));
    #pragma unroll
    for (int off = 1; off < 16; off <<= 1) am = fmaxf(am, __shfl_xor(am, off));
    const float s = fmaxf(am / 7.0f, 1e-8f);                 // IEEE div
    ushort4 o;
    o.x = f2bf(fminf(fmaxf(rintf(v.x / s), -8.f), 7.f) * s); // rintf = half-even
    o.y = f2bf(fminf(fmaxf(rintf(v.y / s), -8.f), 7.f) * s);
    o.z = f2bf(fminf(fmaxf(rintf(v.z / s), -8.f), 7.f) * s);
    o.w = f2bf(fminf(fmaxf(rintf(v.w / s), -8.f), 7.f) * s);
    *(ushort4*)&Bp[(size_t)row * KP + c] = o;
  }
  if (tid < 64)
    Bp[(size_t)row * KP + CDIM + tid] = (tid < 32) ? f2bf(pu[row * 32 + tid]) : (unsigned short)0;
}

// ---------------- K2: activation smooth + fake-quant + lora -> Ap[8192][3136]
__global__ __launch_bounds__(256) void k_aprep(const float* __restrict__ x,
                                               const float* __restrict__ smooth,
                                               const float* __restrict__ pd,
                                               unsigned short* __restrict__ Ap) {
  __shared__ unsigned short xsb[4][3072];   // 24 KB
  __shared__ float plds[4][32][33];         // 16.5 KB
  const int tid = threadIdx.x;
  const int w = tid >> 6, l = tid & 63;
  const int row = blockIdx.x * 4 + w;
  const float* xr = x + (size_t)row * CDIM;

  #pragma unroll 2
  for (int it = 0; it < 12; ++it) {
    const int c = it * 256 + l * 4;
    const float4 xv = *(const float4*)&xr[c];
    const float4 sm = *(const float4*)&smooth[c];
    float4 xs;
    xs.x = xv.x / sm.x; xs.y = xv.y / sm.y;   // exact IEEE div
    xs.z = xv.z / sm.z; xs.w = xv.w / sm.w;
    ushort4 xb;
    xb.x = f2bf(xs.x); xb.y = f2bf(xs.y); xb.z = f2bf(xs.z); xb.w = f2bf(xs.w);
    *(ushort4*)&xsb[w][c] = xb;
    float am = fmaxf(fmaxf(fabsf(xs.x), fabsf(xs.y)), fmaxf(fabsf(xs.z), fabsf(xs.w)));
    #pragma unroll
    for (int off = 1; off < 16; off <<= 1) am = fmaxf(am, __shfl_xor(am, off));
    const float s = fmaxf(am / 7.0f, 1e-8f);
    ushort4 o;
    o.x = f2bf(fminf(fmaxf(rintf(xs.x / s), -8.f), 7.f) * s);
    o.y = f2bf(fminf(fmaxf(rintf(xs.y / s), -8.f), 7.f) * s);
    o.z = f2bf(fminf(fmaxf(rintf(xs.z / s), -8.f), 7.f) * s);
    o.w = f2bf(fminf(fmaxf(rintf(xs.w / s), -8.f), 7.f) * s);
    *(ushort4*)&Ap[(size_t)row * KP + c] = o;
  }
  if (l < 32) Ap[(size_t)row * KP + 3104 + l] = 0;  // zero pad cols
  __syncthreads();

  // lora: thread (ch=tid>>3 in [0,32), rg=tid&7): c = ch*2 + 64*i (+0,+1)
  const int ch = tid >> 3, rg = tid & 7;
  float acc[4][4] = {};
  for (int i = 0; i < 48; ++i) {
    const int c = ch * 2 + i * 64;
    const float4 p0 = *(const float4*)&pd[(size_t)c * 32 + rg * 4];
    const float4 p1 = *(const float4*)&pd[(size_t)(c + 1) * 32 + rg * 4];
    #pragma unroll
    for (int r4 = 0; r4 < 4; ++r4) {
      const unsigned int u = *(const unsigned int*)&xsb[r4][c];
      const float xa = bfu_lo(u), xb = bfu_hi(u);
      acc[r4][0] += xa * p0.x + xb * p1.x;
      acc[r4][1] += xa * p0.y + xb * p1.y;
      acc[r4][2] += xa * p0.z + xb * p1.z;
      acc[r4][3] += xa * p0.w + xb * p1.w;
    }
  }
  #pragma unroll
  for (int r4 = 0; r4 < 4; ++r4)
    #pragma unroll
    for (int j = 0; j < 4; ++j)
      plds[r4][rg * 4 + j][ch] = acc[r4][j];
  __syncthreads();
  if (tid < 128) {
    const int rr = tid >> 5, r = tid & 31;
    float ssum = 0.f;
    #pragma unroll
    for (int cc = 0; cc < 32; ++cc) ssum += plds[rr][r][cc];
    Ap[(size_t)(blockIdx.x * 4 + rr) * KP + 3072 + r] = f2bf(ssum);
  }
}

// ---------------- K3: 256x256-tile GEMM, BK=64 (kk-half regions)
// LDS regions (elements): A(kk,par) = (kk*2+par)*8192 ; B at +32768.
// Region layout [256 rows][4 slots x 8 elems], swizzle: slot ^= (row>>1)&3.
// vmcnt ledger (verified): enter window t with 8 outstanding {kk1(t), kk0(t+1)};
// VM1 at end-ph1 retires kk1(t) (needed ph2); VM3 at end-ph3 retires kk0(t+1)
// (needed ph0 of t+1). Both waits land ~4-5 phases after issue (~1000cy cover).
template<int VM1, int VM3, int DO01, int DO23>
__device__ __forceinline__ void gemm_window(
    unsigned short* lds, f32x4 (&acc)[8][4],
    const unsigned short* Asrc, const unsigned short* Bsrc,
    int tid, int arow, int brow, int fsl, int par, int t) {
  const int A0 = par * 8192;
  const int A1 = 16384 + par * 8192;
  const int B0 = 32768 + par * 8192;
  const int B1 = 49152 + par * 8192;
  const int A1n = 16384 + (par ^ 1) * 8192;
  const int B1n = 49152 + (par ^ 1) * 8192;
  bf16x8 a[4], b[4];

  // ---- phase 0: kk0, mi 0-3 (+ stage A-kk1 of tile t+1)
  #pragma unroll
  for (int ni = 0; ni < 4; ++ni) b[ni] = *(const bf16x8*)&lds[B0 + (brow + ni * 16) * 32 + fsl];
  #pragma unroll
  for (int mi = 0; mi < 4; ++mi) a[mi] = *(const bf16x8*)&lds[A0 + (arow + mi * 16) * 32 + fsl];
  if (DO01) {
    const int kc = (t + 1) * 64 + 32;
    gld16(Asrc + kc, &lds[A1n + tid * 8]);
    gld16(Asrc + (size_t)128 * KP + kc, &lds[A1n + 4096 + tid * 8]);
  }
  BARRIER(); LGKM0();
  __builtin_amdgcn_s_setprio(1);
  #pragma unroll
  for (int mi = 0; mi < 4; ++mi)
    #pragma unroll
    for (int ni = 0; ni < 4; ++ni)
      acc[mi][ni] = __builtin_amdgcn_mfma_f32_16x16x32_bf16(a[mi], b[ni], acc[mi][ni], 0, 0, 0);
  __builtin_amdgcn_s_setprio(0);
  BARRIER();

  // ---- phase 1: kk0, mi 4-7 (+ stage B-kk1 of tile t+1; VM1)
  #pragma unroll
  for (int mi = 0; mi < 4; ++mi) a[mi] = *(const bf16x8*)&lds[A0 + (arow + 64 + mi * 16) * 32 + fsl];
  if (DO01) {
    const int kc = (t + 1) * 64 + 32;
    gld16(Bsrc + kc, &lds[B1n + tid * 8]);
    gld16(Bsrc + (size_t)128 * KP + kc, &lds[B1n + 4096 + tid * 8]);
  }
  BARRIER(); LGKM0();
  __builtin_amdgcn_s_setprio(1);
  #pragma unroll
  for (int mi = 0; mi < 4; ++mi)
    #pragma unroll
    for (int ni = 0; ni < 4; ++ni)
      acc[4 + mi][ni] = __builtin_amdgcn_mfma_f32_16x16x32_bf16(a[mi], b[ni], acc[4 + mi][ni], 0, 0, 0);
  __builtin_amdgcn_s_setprio(0);
  vmw<VM1>();
  BARRIER();

  // ---- phase 2: kk1, mi 0-3 (+ stage A-kk0 of tile t+2 into A0)
  #pragma unroll
  for (int ni = 0; ni < 4; ++ni) b[ni] = *(const bf16x8*)&lds[B1 + (brow + ni * 16) * 32 + fsl];
  #pragma unroll
  for (int mi = 0; mi < 4; ++mi) a[mi] = *(const bf16x8*)&lds[A1 + (arow + mi * 16) * 32 + fsl];
  if (DO23) {
    const int kc = (t + 2) * 64;
    gld16(Asrc + kc, &lds[A0 + tid * 8]);
    gld16(Asrc + (size_t)128 * KP + kc, &lds[A0 + 4096 + tid * 8]);
  }
  BARRIER(); LGKM0();
  __builtin_amdgcn_s_setprio(1);
  #pragma unroll
  for (int mi = 0; mi < 4; ++mi)
    #pragma unroll
    for (int ni = 0; ni < 4; ++ni)
      acc[mi][ni] = __builtin_amdgcn_mfma_f32_16x16x32_bf16(a[mi], b[ni], acc[mi][ni], 0, 0, 0);
  __builtin_amdgcn_s_setprio(0);
  BARRIER();

  // ---- phase 3: kk1, mi 4-7 (+ stage B-kk0 of tile t+2; VM3)
  #pragma unroll
  for (int mi = 0; mi < 4; ++mi) a[mi] = *(const bf16x8*)&lds[A1 + (arow + 64 + mi * 16) * 32 + fsl];
  if (DO23) {
    const int kc = (t + 2) * 64;
    gld16(Bsrc + kc, &lds[B0 + tid * 8]);
    gld16(Bsrc + (size_t)128 * KP + kc, &lds[B0 + 4096 + tid * 8]);
  }
  BARRIER(); LGKM0();
  __builtin_amdgcn_s_setprio(1);
  #pragma unroll
  for (int mi = 0; mi < 4; ++mi)
    #pragma unroll
    for (int ni = 0; ni < 4; ++ni)
      acc[4 + mi][ni] = __builtin_amdgcn_mfma_f32_16x16x32_bf16(a[mi], b[ni], acc[4 + mi][ni], 0, 0, 0);
  __builtin_amdgcn_s_setprio(0);
  vmw<VM3>();
  BARRIER();
}

__global__ __launch_bounds__(512, 2) void k_gemm8(
    const unsigned short* __restrict__ Ap, const unsigned short* __restrict__ Bp,
    const float* __restrict__ bias, float* __restrict__ outp) {
  __shared__ unsigned short lds[65536];  // 128 KiB
  const int tid = threadIdx.x;
  const int w = tid >> 6, l = tid & 63;
  const int wr = w >> 2, wc = w & 3;               // 2M x 4N waves, 128x64 each
  const int s = ((blockIdx.x & 7) * 144) + (blockIdx.x >> 3);  // XCD swizzle (1152%8==0)
  const int bx = s % 36, by = s / 36;
  const int n0 = bx * 256, m0 = by * 256;
  const int arow = wr * 128 + (l & 15);
  const int brow = wc * 64 + (l & 15);
  const int fsl = (((l >> 4) ^ ((l >> 1) & 3)) << 3);  // slot ^= (row>>1)&3
  const int sr = tid >> 2;                             // staging row 0..127
  const int ss = (((tid & 3) ^ ((sr >> 1) & 3)) << 3); // pre-swizzled source slot
  const unsigned short* Asrc = Ap + (size_t)(m0 + sr) * KP + ss;
  const unsigned short* Bsrc = Bp + (size_t)(n0 + sr) * KP + ss;
  f32x4 acc[8][4] = {};

  // prologue: stage kk0(0), kk1(0), kk0(1); retire kk0(0)
  gld16(Asrc, &lds[tid * 8]);                 gld16(Asrc + (size_t)128 * KP, &lds[4096 + tid * 8]);
  gld16(Bsrc, &lds[32768 + tid * 8]);         gld16(Bsrc + (size_t)128 * KP, &lds[36864 + tid * 8]);
  gld16(Asrc + 32, &lds[16384 + tid * 8]);    gld16(Asrc + (size_t)128 * KP + 32, &lds[20480 + tid * 8]);
  gld16(Bsrc + 32, &lds[49152 + tid * 8]);    gld16(Bsrc + (size_t)128 * KP + 32, &lds[53248 + tid * 8]);
  gld16(Asrc + 64, &lds[8192 + tid * 8]);     gld16(Asrc + (size_t)128 * KP + 64, &lds[12288 + tid * 8]);
  gld16(Bsrc + 64, &lds[40960 + tid * 8]);    gld16(Bsrc + (size_t)128 * KP + 64, &lds[45056 + tid * 8]);
  vmw<8>(); BARRIER();

  #pragma unroll 1
  for (int t = 0; t <= NT - 3; ++t)
    gemm_window<8, 8, 1, 1>(lds, acc, Asrc, Bsrc, tid, arow, brow, fsl, t & 1, t);
  gemm_window<8, 4, 1, 0>(lds, acc, Asrc, Bsrc, tid, arow, brow, fsl, (NT - 2) & 1, NT - 2);
  gemm_window<0, 63, 0, 0>(lds, acc, Asrc, Bsrc, tid, arow, brow, fsl, (NT - 1) & 1, NT - 1);

  #pragma unroll
  for (int ni = 0; ni < 4; ++ni) {
    const int gn = n0 + wc * 64 + ni * 16 + (l & 15);
    const float bv = bias[gn];
    #pragma unroll
    for (int q = 0; q < 8; ++q) {
      const int gm = m0 + wr * 128 + q * 16 + (l >> 4) * 4;
      #pragma unroll
      for (int j = 0; j < 4; ++j)
        outp[(size_t)(gm + j) * NOUT + gn] = acc[q][ni][j] + bv;
    }
  }
}

// ---------------- K4: in-place RMSNorm + RoPE on q,k columns of d_out (f32)
// 2 heads per wave (32 lanes x float4 = 128 cols), 48 head-slots / 8 per iter
__global__ void k_epi(float* __restrict__ outp,
                      const float* __restrict__ nqw, const float* __restrict__ nkw,
                      const float* __restrict__ fcos, const float* __restrict__ fsin) {
  const int m = blockIdx.x;
  const int sidx = m & 4095;           // m = b*4096 + s
  const int w = threadIdx.x >> 6, l = threadIdx.x & 63;
  const int half = l >> 5, l32 = l & 31;
  const float2 cs = *(const float2*)&fcos[(size_t)sidx * 64 + 2 * l32];
  const float2 sn = *(const float2*)&fsin[(size_t)sidx * 64 + 2 * l32];
  const float4 wq = *(const float4*)&nqw[4 * l32];
  const float4 wk = *(const float4*)&nkw[4 * l32];
  #pragma unroll
  for (int it = 0; it < 6; ++it) {
    const int hh = it * 8 + w * 2 + half;   // 0..47
    float* p = outp + (size_t)m * NOUT + hh * 128 + 4 * l32;
    const float4 v = *(const float4*)p;
    float ssum = v.x * v.x + v.y * v.y + v.z * v.z + v.w * v.w;
    #pragma unroll
    for (int off = 1; off < 32; off <<= 1) ssum += __shfl_xor(ssum, off);
    const float rinv = 1.0f / sqrtf(ssum * (1.0f / 128.0f) + 1e-6f);
    const float4 nw = (hh < 24) ? wq : wk;
    const float a0 = v.x * rinv * nw.x, b0 = v.y * rinv * nw.y;
    const float a1 = v.z * rinv * nw.z, b1 = v.w * rinv * nw.w;
    float4 o;
    o.x = a0 * cs.x - b0 * sn.x;  o.y = a0 * sn.x + b0 * cs.x;
    o.z = a1 * cs.y - b1 * sn.y;  o.w = a1 * sn.y + b1 * cs.y;
    *(float4*)p = o;
  }
}

extern "C" void kernel_launch(void* const* d_in, const int* in_sizes, int n_in,
                              void* d_out, int out_size, void* d_ws, size_t ws_size,
                              hipStream_t stream) {
  const float* x      = (const float*)d_in[0];
  const float* smooth = (const float*)d_in[1];
  const float* weight = (const float*)d_in[2];
  const float* pd     = (const float*)d_in[3];
  const float* pu     = (const float*)d_in[4];
  const float* bias   = (const float*)d_in[5];
  const float* nqw    = (const float*)d_in[6];
  const float* nkw    = (const float*)d_in[7];
  const float* fcos   = (const float*)d_in[8];
  const float* fsin   = (const float*)d_in[9];
  float* out = (float*)d_out;

  unsigned short* Ap = (unsigned short*)d_ws;                      // 51,380,224 B
  unsigned short* Bp = (unsigned short*)((char*)d_ws + 51380224);  // 57,802,752 B

  k_wquant<<<dim3(NOUT), dim3(256), 0, stream>>>(weight, pu, Bp);
  k_aprep<<<dim3(MROWS / 4), dim3(256), 0, stream>>>(x, smooth, pd, Ap);
  k_gemm8<<<dim3(1152), dim3(512), 0, stream>>>(Ap, Bp, bias, out);
  k_epi<<<dim3(MROWS), dim3(256), 0, stream>>>(out, nqw, nkw, fcos, fsin);
}

// Round 5
// 593.682 us; speedup vs baseline: 1.7270x; 1.1254x over previous
//
#include <hip/hip_runtime.h>

#define KP    3136   // 3072 quant + 32 lora + 32 zero-pad
#define CDIM  3072
#define MROWS 8192
#define NOUT  9216
#define NT    49     // KP / 64 K-tiles

typedef __bf16 bf16x8 __attribute__((ext_vector_type(8)));
typedef float f32x4 __attribute__((ext_vector_type(4)));

__device__ __forceinline__ unsigned short f2bf(float f) {
  union { float f; unsigned int u; } v; v.f = f;
  unsigned int u = v.u;
  return (unsigned short)((u + 0x7fffu + ((u >> 16) & 1u)) >> 16);  // RNE
}
__device__ __forceinline__ float bfu_lo(unsigned int u) {
  union { unsigned int v; float f; } x; x.v = u << 16; return x.f;
}
__device__ __forceinline__ float bfu_hi(unsigned int u) {
  union { unsigned int v; float f; } x; x.v = u & 0xffff0000u; return x.f;
}
__device__ __forceinline__ void gld16(const void* g, void* l) {
  __builtin_amdgcn_global_load_lds(
      (const __attribute__((address_space(1))) void*)g,
      (__attribute__((address_space(3))) void*)l, 16, 0, 0);
}

#define BARRIER() asm volatile("s_barrier" ::: "memory")
#define LGKM0()   asm volatile("s_waitcnt lgkmcnt(0)" ::: "memory")

template<int N> __device__ __forceinline__ void vmw() {
  if constexpr (N == 8)      asm volatile("s_waitcnt vmcnt(8)" ::: "memory");
  else if constexpr (N == 4) asm volatile("s_waitcnt vmcnt(4)" ::: "memory");
  else if constexpr (N == 0) asm volatile("s_waitcnt vmcnt(0)" ::: "memory");
  // N==63: no wait
}

// ---------------- K1: weight fake-quant + proj_up pack -> Bp[9216][3136] bf16
__global__ __launch_bounds__(256) void k_wquant(const float* __restrict__ w,
                                                const float* __restrict__ pu,
                                                unsigned short* __restrict__ Bp) {
  const int row = blockIdx.x;
  const int tid = threadIdx.x;
  #pragma unroll
  for (int it = 0; it < 3; ++it) {
    const int c = it * 1024 + tid * 4;
    const float4 v = *(const float4*)&w[(size_t)row * CDIM + c];
    float am = fmaxf(fmaxf(fabsf(v.x), fabsf(v.y)), fmaxf(fabsf(v.z), fabsf(v.w)));
    #pragma unroll
    for (int off = 1; off < 16; off <<= 1) am = fmaxf(am, __shfl_xor(am, off));
    const float s = fmaxf(am / 7.0f, 1e-8f);                 // IEEE div
    ushort4 o;
    o.x = f2bf(fminf(fmaxf(rintf(v.x / s), -8.f), 7.f) * s); // rintf = half-even
    o.y = f2bf(fminf(fmaxf(rintf(v.y / s), -8.f), 7.f) * s);
    o.z = f2bf(fminf(fmaxf(rintf(v.z / s), -8.f), 7.f) * s);
    o.w = f2bf(fminf(fmaxf(rintf(v.w / s), -8.f), 7.f) * s);
    *(ushort4*)&Bp[(size_t)row * KP + c] = o;
  }
  if (tid < 64)
    Bp[(size_t)row * KP + CDIM + tid] = (tid < 32) ? f2bf(pu[row * 32 + tid]) : (unsigned short)0;
}

// ---------------- K2: activation smooth + fake-quant + lora -> Ap[8192][3136]
__global__ __launch_bounds__(256) void k_aprep(const float* __restrict__ x,
                                               const float* __restrict__ smooth,
                                               const float* __restrict__ pd,
                                               unsigned short* __restrict__ Ap) {
  __shared__ unsigned short xsb[4][3072];   // 24 KB
  __shared__ float plds[4][32][33];         // 16.5 KB
  const int tid = threadIdx.x;
  const int w = tid >> 6, l = tid & 63;
  const int row = blockIdx.x * 4 + w;
  const float* xr = x + (size_t)row * CDIM;

  #pragma unroll 2
  for (int it = 0; it < 12; ++it) {
    const int c = it * 256 + l * 4;
    const float4 xv = *(const float4*)&xr[c];
    const float4 sm = *(const float4*)&smooth[c];
    float4 xs;
    xs.x = xv.x / sm.x; xs.y = xv.y / sm.y;   // exact IEEE div
    xs.z = xv.z / sm.z; xs.w = xv.w / sm.w;
    ushort4 xb;
    xb.x = f2bf(xs.x); xb.y = f2bf(xs.y); xb.z = f2bf(xs.z); xb.w = f2bf(xs.w);
    *(ushort4*)&xsb[w][c] = xb;
    float am = fmaxf(fmaxf(fabsf(xs.x), fabsf(xs.y)), fmaxf(fabsf(xs.z), fabsf(xs.w)));
    #pragma unroll
    for (int off = 1; off < 16; off <<= 1) am = fmaxf(am, __shfl_xor(am, off));
    const float s = fmaxf(am / 7.0f, 1e-8f);
    ushort4 o;
    o.x = f2bf(fminf(fmaxf(rintf(xs.x / s), -8.f), 7.f) * s);
    o.y = f2bf(fminf(fmaxf(rintf(xs.y / s), -8.f), 7.f) * s);
    o.z = f2bf(fminf(fmaxf(rintf(xs.z / s), -8.f), 7.f) * s);
    o.w = f2bf(fminf(fmaxf(rintf(xs.w / s), -8.f), 7.f) * s);
    *(ushort4*)&Ap[(size_t)row * KP + c] = o;
  }
  if (l < 32) Ap[(size_t)row * KP + 3104 + l] = 0;  // zero pad cols
  __syncthreads();

  // lora: thread (ch=tid>>3 in [0,32), rg=tid&7): c = ch*2 + 64*i (+0,+1)
  const int ch = tid >> 3, rg = tid & 7;
  float acc[4][4] = {};
  for (int i = 0; i < 48; ++i) {
    const int c = ch * 2 + i * 64;
    const float4 p0 = *(const float4*)&pd[(size_t)c * 32 + rg * 4];
    const float4 p1 = *(const float4*)&pd[(size_t)(c + 1) * 32 + rg * 4];
    #pragma unroll
    for (int r4 = 0; r4 < 4; ++r4) {
      const unsigned int u = *(const unsigned int*)&xsb[r4][c];
      const float xa = bfu_lo(u), xb = bfu_hi(u);
      acc[r4][0] += xa * p0.x + xb * p1.x;
      acc[r4][1] += xa * p0.y + xb * p1.y;
      acc[r4][2] += xa * p0.z + xb * p1.z;
      acc[r4][3] += xa * p0.w + xb * p1.w;
    }
  }
  #pragma unroll
  for (int r4 = 0; r4 < 4; ++r4)
    #pragma unroll
    for (int j = 0; j < 4; ++j)
      plds[r4][rg * 4 + j][ch] = acc[r4][j];
  __syncthreads();
  if (tid < 128) {
    const int rr = tid >> 5, r = tid & 31;
    float ssum = 0.f;
    #pragma unroll
    for (int cc = 0; cc < 32; ++cc) ssum += plds[rr][r][cc];
    Ap[(size_t)(blockIdx.x * 4 + rr) * KP + 3072 + r] = f2bf(ssum);
  }
}

// ---------------- K3: 256x256-tile GEMM + fused bias/RMSNorm/RoPE epilogue
// LDS regions (elements): A(kk,par) = (kk*2+par)*8192 ; B at +32768.
// Region layout [256 rows][4 slots x 8 elems], swizzle: slot ^= (row>>1)&3.
// vmcnt ledger: enter window t with 8 outstanding {kk1(t), kk0(t+1)};
// VM1 end-ph1 retires kk1(t); VM3 end-ph3 retires kk0(t+1).
template<int VM1, int VM3, int DO01, int DO23>
__device__ __forceinline__ void gemm_window(
    unsigned short* lds, f32x4 (&acc)[8][4],
    const unsigned short* Asrc, const unsigned short* Bsrc,
    int tid, int arow, int brow, int fsl, int par, int t) {
  const int A0 = par * 8192;
  const int A1 = 16384 + par * 8192;
  const int B0 = 32768 + par * 8192;
  const int B1 = 49152 + par * 8192;
  const int A1n = 16384 + (par ^ 1) * 8192;
  const int B1n = 49152 + (par ^ 1) * 8192;
  bf16x8 a[4], b[4];

  // ---- phase 0: kk0, mi 0-3 (+ stage A-kk1 of tile t+1)
  #pragma unroll
  for (int ni = 0; ni < 4; ++ni) b[ni] = *(const bf16x8*)&lds[B0 + (brow + ni * 16) * 32 + fsl];
  #pragma unroll
  for (int mi = 0; mi < 4; ++mi) a[mi] = *(const bf16x8*)&lds[A0 + (arow + mi * 16) * 32 + fsl];
  if (DO01) {
    const int kc = (t + 1) * 64 + 32;
    gld16(Asrc + kc, &lds[A1n + tid * 8]);
    gld16(Asrc + (size_t)128 * KP + kc, &lds[A1n + 4096 + tid * 8]);
  }
  BARRIER(); LGKM0();
  __builtin_amdgcn_s_setprio(1);
  #pragma unroll
  for (int mi = 0; mi < 4; ++mi)
    #pragma unroll
    for (int ni = 0; ni < 4; ++ni)
      acc[mi][ni] = __builtin_amdgcn_mfma_f32_16x16x32_bf16(a[mi], b[ni], acc[mi][ni], 0, 0, 0);
  __builtin_amdgcn_s_setprio(0);
  BARRIER();

  // ---- phase 1: kk0, mi 4-7 (+ stage B-kk1 of tile t+1; VM1)
  #pragma unroll
  for (int mi = 0; mi < 4; ++mi) a[mi] = *(const bf16x8*)&lds[A0 + (arow + 64 + mi * 16) * 32 + fsl];
  if (DO01) {
    const int kc = (t + 1) * 64 + 32;
    gld16(Bsrc + kc, &lds[B1n + tid * 8]);
    gld16(Bsrc + (size_t)128 * KP + kc, &lds[B1n + 4096 + tid * 8]);
  }
  BARRIER(); LGKM0();
  __builtin_amdgcn_s_setprio(1);
  #pragma unroll
  for (int mi = 0; mi < 4; ++mi)
    #pragma unroll
    for (int ni = 0; ni < 4; ++ni)
      acc[4 + mi][ni] = __builtin_amdgcn_mfma_f32_16x16x32_bf16(a[mi], b[ni], acc[4 + mi][ni], 0, 0, 0);
  __builtin_amdgcn_s_setprio(0);
  vmw<VM1>();
  BARRIER();

  // ---- phase 2: kk1, mi 0-3 (+ stage A-kk0 of tile t+2 into A0)
  #pragma unroll
  for (int ni = 0; ni < 4; ++ni) b[ni] = *(const bf16x8*)&lds[B1 + (brow + ni * 16) * 32 + fsl];
  #pragma unroll
  for (int mi = 0; mi < 4; ++mi) a[mi] = *(const bf16x8*)&lds[A1 + (arow + mi * 16) * 32 + fsl];
  if (DO23) {
    const int kc = (t + 2) * 64;
    gld16(Asrc + kc, &lds[A0 + tid * 8]);
    gld16(Asrc + (size_t)128 * KP + kc, &lds[A0 + 4096 + tid * 8]);
  }
  BARRIER(); LGKM0();
  __builtin_amdgcn_s_setprio(1);
  #pragma unroll
  for (int mi = 0; mi < 4; ++mi)
    #pragma unroll
    for (int ni = 0; ni < 4; ++ni)
      acc[mi][ni] = __builtin_amdgcn_mfma_f32_16x16x32_bf16(a[mi], b[ni], acc[mi][ni], 0, 0, 0);
  __builtin_amdgcn_s_setprio(0);
  BARRIER();

  // ---- phase 3: kk1, mi 4-7 (+ stage B-kk0 of tile t+2; VM3)
  #pragma unroll
  for (int mi = 0; mi < 4; ++mi) a[mi] = *(const bf16x8*)&lds[A1 + (arow + 64 + mi * 16) * 32 + fsl];
  if (DO23) {
    const int kc = (t + 2) * 64;
    gld16(Bsrc + kc, &lds[B0 + tid * 8]);
    gld16(Bsrc + (size_t)128 * KP + kc, &lds[B0 + 4096 + tid * 8]);
  }
  BARRIER(); LGKM0();
  __builtin_amdgcn_s_setprio(1);
  #pragma unroll
  for (int mi = 0; mi < 4; ++mi)
    #pragma unroll
    for (int ni = 0; ni < 4; ++ni)
      acc[4 + mi][ni] = __builtin_amdgcn_mfma_f32_16x16x32_bf16(a[mi], b[ni], acc[4 + mi][ni], 0, 0, 0);
  __builtin_amdgcn_s_setprio(0);
  vmw<VM3>();
  BARRIER();
}

__global__ __launch_bounds__(512, 2) void k_gemm8(
    const unsigned short* __restrict__ Ap, const unsigned short* __restrict__ Bp,
    const float* __restrict__ bias,
    const float* __restrict__ nqw, const float* __restrict__ nkw,
    const float* __restrict__ fcos, const float* __restrict__ fsin,
    float* __restrict__ outp) {
  __shared__ unsigned short lds[65536];  // 128 KiB
  const int tid = threadIdx.x;
  const int w = tid >> 6, l = tid & 63;
  const int wr = w >> 2, wc = w & 3;               // 2M x 4N waves, 128x64 each
  // 2D-chunked XCD swizzle: XCD owns by-band [4*xcd, 4*xcd+4), swept in 4
  // bx-chunks of 9. Bijective: blk = (t' + chunk*36)*8 + xcd.
  const int xcd = blockIdx.x & 7;
  const int jj = blockIdx.x >> 3;      // 0..143
  const int chunk = jj / 36;           // 0..3
  const int tt = jj - chunk * 36;      // 0..35
  const int by = xcd * 4 + tt / 9;
  const int bx = chunk * 9 + tt % 9;
  const int n0 = bx * 256, m0 = by * 256;
  const int arow = wr * 128 + (l & 15);
  const int brow = wc * 64 + (l & 15);
  const int fsl = (((l >> 4) ^ ((l >> 1) & 3)) << 3);  // slot ^= (row>>1)&3
  const int sr = tid >> 2;                             // staging row 0..127
  const int ss = (((tid & 3) ^ ((sr >> 1) & 3)) << 3); // pre-swizzled source slot
  const unsigned short* Asrc = Ap + (size_t)(m0 + sr) * KP + ss;
  const unsigned short* Bsrc = Bp + (size_t)(n0 + sr) * KP + ss;
  f32x4 acc[8][4] = {};

  // prologue: stage kk0(0), kk1(0), kk0(1); retire kk0(0)
  gld16(Asrc, &lds[tid * 8]);                 gld16(Asrc + (size_t)128 * KP, &lds[4096 + tid * 8]);
  gld16(Bsrc, &lds[32768 + tid * 8]);         gld16(Bsrc + (size_t)128 * KP, &lds[36864 + tid * 8]);
  gld16(Asrc + 32, &lds[16384 + tid * 8]);    gld16(Asrc + (size_t)128 * KP + 32, &lds[20480 + tid * 8]);
  gld16(Bsrc + 32, &lds[49152 + tid * 8]);    gld16(Bsrc + (size_t)128 * KP + 32, &lds[53248 + tid * 8]);
  gld16(Asrc + 64, &lds[8192 + tid * 8]);     gld16(Asrc + (size_t)128 * KP + 64, &lds[12288 + tid * 8]);
  gld16(Bsrc + 64, &lds[40960 + tid * 8]);    gld16(Bsrc + (size_t)128 * KP + 64, &lds[45056 + tid * 8]);
  vmw<8>(); BARRIER();

  #pragma unroll 1
  for (int t = 0; t <= NT - 3; ++t)
    gemm_window<8, 8, 1, 1>(lds, acc, Asrc, Bsrc, tid, arow, brow, fsl, t & 1, t);
  gemm_window<8, 4, 1, 0>(lds, acc, Asrc, Bsrc, tid, arow, brow, fsl, (NT - 2) & 1, NT - 2);
  gemm_window<0, 63, 0, 0>(lds, acc, Asrc, Bsrc, tid, arow, brow, fsl, (NT - 1) & 1, NT - 1);

  // ---------------- fused epilogue ----------------
  // bias first (reference: out = gemm + bias, THEN norm/rope)
  float bv[4];
  #pragma unroll
  for (int ni = 0; ni < 4; ++ni) bv[ni] = bias[n0 + wc * 64 + ni * 16 + (l & 15)];
  #pragma unroll
  for (int q = 0; q < 8; ++q)
    #pragma unroll
    for (int ni = 0; ni < 4; ++ni)
      #pragma unroll
      for (int j = 0; j < 4; ++j) acc[q][ni][j] += bv[ni];

  const int g16 = l >> 4;       // row group 0..3
  const int l16 = l & 15;

  if (n0 < 6144) {
    // q/k block: RMSNorm (weight) + RoPE, fully in-register + 4KB LDS exchange
    const float* nwt = (n0 < 3072) ? nqw : nkw;
    float nw[4];
    #pragma unroll
    for (int ni = 0; ni < 4; ++ni) nw[ni] = nwt[(wc & 1) * 64 + ni * 16 + l16];

    float part[8][4];
    #pragma unroll
    for (int q = 0; q < 8; ++q)
      #pragma unroll
      for (int j = 0; j < 4; ++j) {
        float ssum = 0.f;
        #pragma unroll
        for (int ni = 0; ni < 4; ++ni) ssum += acc[q][ni][j] * acc[q][ni][j];
        #pragma unroll
        for (int off = 1; off < 16; off <<= 1) ssum += __shfl_xor(ssum, off);
        part[q][j] = ssum;   // per-row partial over this wave's 64 cols
      }

    __syncthreads();                    // LDS regions done; reuse as sq
    float* sq = (float*)lds;            // [wr][r128][wc>>1][wc&1] = [2][128][2][2]
    if (l16 == 0) {
      #pragma unroll
      for (int q = 0; q < 8; ++q)
        #pragma unroll
        for (int j = 0; j < 4; ++j) {
          const int r128 = q * 16 + g16 * 4 + j;
          sq[(((wr * 128 + r128) * 2 + (wc >> 1)) * 2) + (wc & 1)] = part[q][j];
        }
    }
    __syncthreads();

    #pragma unroll
    for (int q = 0; q < 8; ++q) {
      #pragma unroll
      for (int j = 0; j < 4; ++j) {
        const int r128 = q * 16 + g16 * 4 + j;
        const float other = sq[(((wr * 128 + r128) * 2 + (wc >> 1)) * 2) + ((wc & 1) ^ 1)];
        const float rinv = 1.0f / sqrtf((part[q][j] + other) * (1.0f / 128.0f) + 1e-6f);
        const int row = m0 + wr * 128 + r128;
        const int sidx = row & 4095;
        #pragma unroll
        for (int ni = 0; ni < 4; ++ni) {
          const int p = (wc & 1) * 32 + ni * 8 + (l16 >> 1);
          const float cv = fcos[(size_t)sidx * 64 + p];
          const float sv = fsin[(size_t)sidx * 64 + p];
          const float v = acc[q][ni][j] * rinv * nw[ni];
          const float o = __shfl_xor(v, 1);
          const float res = ((l & 1) == 0) ? (v * cv - o * sv) : (o * sv + v * cv);
          __builtin_nontemporal_store(res, &outp[(size_t)row * NOUT + n0 + wc * 64 + ni * 16 + l16]);
        }
      }
    }
  } else {
    // v block: bias only
    #pragma unroll
    for (int ni = 0; ni < 4; ++ni) {
      const int gn = n0 + wc * 64 + ni * 16 + l16;
      #pragma unroll
      for (int q = 0; q < 8; ++q) {
        const int gm = m0 + wr * 128 + q * 16 + g16 * 4;
        #pragma unroll
        for (int j = 0; j < 4; ++j)
          __builtin_nontemporal_store(acc[q][ni][j], &outp[(size_t)(gm + j) * NOUT + gn]);
      }
    }
  }
}

extern "C" void kernel_launch(void* const* d_in, const int* in_sizes, int n_in,
                              void* d_out, int out_size, void* d_ws, size_t ws_size,
                              hipStream_t stream) {
  const float* x      = (const float*)d_in[0];
  const float* smooth = (const float*)d_in[1];
  const float* weight = (const float*)d_in[2];
  const float* pd     = (const float*)d_in[3];
  const float* pu     = (const float*)d_in[4];
  const float* bias   = (const float*)d_in[5];
  const float* nqw    = (const float*)d_in[6];
  const float* nkw    = (const float*)d_in[7];
  const float* fcos   = (const float*)d_in[8];
  const float* fsin   = (const float*)d_in[9];
  float* out = (float*)d_out;

  unsigned short* Ap = (unsigned short*)d_ws;                      // 51,380,224 B
  unsigned short* Bp = (unsigned short*)((char*)d_ws + 51380224);  // 57,802,752 B

  k_wquant<<<dim3(NOUT), dim3(256), 0, stream>>>(weight, pu, Bp);
  k_aprep<<<dim3(MROWS / 4), dim3(256), 0, stream>>>(x, smooth, pd, Ap);
  k_gemm8<<<dim3(1152), dim3(512), 0, stream>>>(Ap, Bp, bias, nqw, nkw, fcos, fsin, out);
}